// Round 9
// baseline (22.136 us; speedup 1.0000x reference)
//
#include <hip/hip_runtime.h>

// GPTQ W4A32 linear via bf16 MFMA, magic-mantissa dequant.
// out(16,11008) = x(16,4096) @ W,  W[k][n] = s[g][n]*(w4[k][n] - z4[g][n]).
// bf16 bits (0x4380|w) == 256+2w exactly -> MFMA on raw nibbles gives
// P_raw = 256*X + 2*P per group (X = group-sum of bf16-rounded x):
// out += (s/2)*P_raw - s*(128+z)*X.  Mask-trick nibble order k={0,4,1,5,2,6,3,7}.
//
// R9 structure: prep kernel materializes the bf16 A-operand ONCE in exact
// MFMA fragment order (xbf[128 k-tiles][64 lanes][8 bf16]) + Xtab[32][16];
// the main kernel has NO LDS, NO barriers, NO casts -- per wave it streams
// {16B A-frag (L1-hot, shared by all n-blocks), qweight dword, 8-op dequant,
// MFMA}. R4's per-block staging redid that cast 172x behind two barriers.
// Epilogue: verified partials + reduce kernel (no atomics, no fences -- R5).

#define M_DIM 16
#define K_DIM 4096
#define N_DIM 11008
#define GS 128
#define NG (K_DIM / GS)          // 32 groups
#define KSPLIT 8
#define GPB 4                    // groups per main block (= NG/KSPLIT)
#define BLOCKN 64                // 4 waves x 16 n
#define NTHREADS 256

typedef __attribute__((ext_vector_type(8))) short short8;
typedef __attribute__((ext_vector_type(4))) float f32x4;

__device__ __forceinline__ float bfl(unsigned w) {
    union { unsigned u; float f; } c; c.u = w << 16; return c.f;
}
__device__ __forceinline__ float bfh(unsigned w) {
    union { unsigned u; float f; } c; c.u = w & 0xFFFF0000u; return c.f;
}

// One block per group g: build A-fragments for k-tiles 4g..4g+3 and Xtab[g][*].
// Thread t: m = t>>4, c = t&15 -> 8 consecutive k at g*128 + c*8.
// Fragment layout: tile T holds lanes l = lhi*16 + m, lane's 8 bf16 are
// x[m][T*32 + lhi*8 + {0,4,1,5,2,6,3,7}] (cvt_pk pair order).
__global__ __launch_bounds__(256) void qlin_prep(
    const float* __restrict__ x,
    unsigned short* __restrict__ xbf,   // [128][512] halfwords
    float* __restrict__ Xtab)           // [32][16]
{
    const int g = blockIdx.x;
    const int t = threadIdx.x;
    const int m = t >> 4;
    const int c = t & 15;
    const float* xp = x + (size_t)m * K_DIM + g * GS + c * 8;

    float v[8];
#pragma unroll
    for (int j = 0; j < 8; ++j) v[j] = xp[j];

    union { short8 s; unsigned u[4]; } pk;
    asm("v_cvt_pk_bf16_f32 %0, %1, %2" : "=v"(pk.u[0]) : "v"(v[0]), "v"(v[4]));
    asm("v_cvt_pk_bf16_f32 %0, %1, %2" : "=v"(pk.u[1]) : "v"(v[1]), "v"(v[5]));
    asm("v_cvt_pk_bf16_f32 %0, %1, %2" : "=v"(pk.u[2]) : "v"(v[2]), "v"(v[6]));
    asm("v_cvt_pk_bf16_f32 %0, %1, %2" : "=v"(pk.u[3]) : "v"(v[3]), "v"(v[7]));

    const int T    = g * 4 + (c >> 2);
    const int lane = (c & 3) * 16 + m;
    *(short8*)(xbf + (size_t)T * 512 + lane * 8) = pk.s;

    float s = 0.f;
#pragma unroll
    for (int p = 0; p < 4; ++p) s += bfl(pk.u[p]) + bfh(pk.u[p]);
    // threads m*16+c are contiguous: reduce over c within each 16-lane group
    s += __shfl_xor(s, 1, 16);
    s += __shfl_xor(s, 2, 16);
    s += __shfl_xor(s, 4, 16);
    s += __shfl_xor(s, 8, 16);
    if (c == 0) Xtab[g * 16 + m] = s;
}

__global__ __launch_bounds__(NTHREADS) void qlin_mfma(
    const int*   __restrict__ qweight,
    const float* __restrict__ scales,
    const int*   __restrict__ qzeros,
    const unsigned short* __restrict__ xbf,
    const float* __restrict__ Xtab,
    float*       __restrict__ part)     // [KSPLIT][16][N]
{
    const int tid  = threadIdx.x;
    const int lane = tid & 63, wave = tid >> 6;
    const int lmod = lane & 15, lhi = lane >> 4;
    const int n    = blockIdx.x * BLOCKN + wave * 16 + lmod;
    const int zsh  = (n & 7) * 4;
    const int G0   = blockIdx.y * GPB;

    f32x4 outacc = {0.f, 0.f, 0.f, 0.f};

#pragma unroll
    for (int g = 0; g < GPB; ++g) {
        const int G = G0 + g;
        const float s = scales[(size_t)G * N_DIM + n];
        const unsigned zq =
            (unsigned)qzeros[(size_t)G * (N_DIM / 8) + (n >> 3)];

        f32x4 acc = {0.f, 0.f, 0.f, 0.f};
#pragma unroll
        for (int t = 0; t < 4; ++t) {
            const int T = G * 4 + t;
            const short8 a = *(const short8*)(xbf + (size_t)T * 512 + lane * 8);
            const unsigned q =
                (unsigned)qweight[(size_t)(T * 4 + lhi) * N_DIM + n];
            union { short8 v; unsigned u[4]; } b;
            b.u[0] = ( q        & 0x000F000Fu) | 0x43804380u;
            b.u[1] = ((q >> 4)  & 0x000F000Fu) | 0x43804380u;
            b.u[2] = ((q >> 8)  & 0x000F000Fu) | 0x43804380u;
            b.u[3] = ((q >> 12) & 0x000F000Fu) | 0x43804380u;
            acc = __builtin_amdgcn_mfma_f32_16x16x32_bf16(a, b.v, acc, 0, 0, 0);
        }
        const f32x4 x4 = *(const f32x4*)(Xtab + G * 16 + lhi * 4);
        const float z  = (float)((zq >> zsh) & 15u);
        const float s2 = 0.5f * s;
        const float zc = -s * (128.0f + z);
#pragma unroll
        for (int r = 0; r < 4; ++r)
            outacc[r] = fmaf(s2, acc[r], fmaf(zc, x4[r], outacc[r]));
    }

#pragma unroll
    for (int r = 0; r < 4; ++r)
        part[(size_t)(blockIdx.y * M_DIM + lhi * 4 + r) * N_DIM + n] = outacc[r];
}

__global__ __launch_bounds__(256) void qlin_reduce(
    const float* __restrict__ part, float* __restrict__ out)
{
    const int i = blockIdx.x * 256 + threadIdx.x;   // over M*N
    if (i < M_DIM * N_DIM) {
        float s = 0.f;
#pragma unroll
        for (int c = 0; c < KSPLIT; ++c)
            s += part[(size_t)c * M_DIM * N_DIM + i];
        out[i] = s;
    }
}

extern "C" void kernel_launch(void* const* d_in, const int* in_sizes, int n_in,
                              void* d_out, int out_size, void* d_ws, size_t ws_size,
                              hipStream_t stream) {
    const float* x       = (const float*)d_in[0];
    const int*   qweight = (const int*)d_in[1];
    const float* scales  = (const float*)d_in[2];
    const int*   qzeros  = (const int*)d_in[3];
    float*       out     = (float*)d_out;

    const size_t xbf_bytes  = (size_t)128 * 512 * sizeof(unsigned short); // 128 KiB
    const size_t xtab_bytes = (size_t)NG * 16 * sizeof(float);            // 2 KiB
    unsigned short* xbf  = (unsigned short*)d_ws;
    float*          Xtab = (float*)((char*)d_ws + xbf_bytes);
    float*          part = (float*)((char*)d_ws + xbf_bytes +
                                    ((xtab_bytes + 255) & ~(size_t)255));

    qlin_prep<<<NG, 256, 0, stream>>>(x, xbf, Xtab);
    dim3 grid(N_DIM / BLOCKN, KSPLIT);              // (172, 8)
    qlin_mfma<<<grid, NTHREADS, 0, stream>>>(qweight, scales, qzeros,
                                             xbf, Xtab, part);
    qlin_reduce<<<(M_DIM * N_DIM + 255) / 256, 256, 0, stream>>>(part, out);
}